// Round 11
// baseline (192.263 us; speedup 1.0000x reference)
//
#include <hip/hip_runtime.h>
#include <hip/hip_bf16.h>
#include <stdint.h>

typedef __attribute__((ext_vector_type(8))) short bf16x8;
typedef __attribute__((ext_vector_type(4))) float f32x4;

#define S_2LOG2E 2.8853900817779268f   // 2*log2(e): tanh(x)=1-2/(2^(x*S)+1)

#if __has_builtin(__builtin_amdgcn_exp2f)
#define EXP2F(x) __builtin_amdgcn_exp2f(x)
#else
#define EXP2F(x) __expf((x) * 0.6931471805599453f)
#endif
#if __has_builtin(__builtin_amdgcn_rcpf)
#define RCPF(x) __builtin_amdgcn_rcpf(x)
#else
#define RCPF(x) (1.0f / (x))
#endif

// tanh given pre-scaled argument z = S*(x) : returns tanh(x)
__device__ __forceinline__ float tanh_z(float z) {
    float e = EXP2F(z);
    float r = RCPF(e + 1.0f);
    return fmaf(-2.0f, r, 1.0f);
}
__device__ __forceinline__ float tanh_fast(float x) {   // prep only
    float e = __expf(2.0f * x);
    return 1.0f - 2.0f / (e + 1.0f);
}

// ---- bf16 pack via native v_cvt_pk_bf16_f32 (RNE) ----
__device__ __forceinline__ bf16x8 pack2(float4 a, float4 b) {
    union { bf16x8 v; __hip_bfloat162 h[4]; } r;
    r.h[0] = __float22bfloat162_rn(make_float2(a.x, a.y));
    r.h[1] = __float22bfloat162_rn(make_float2(a.z, a.w));
    r.h[2] = __float22bfloat162_rn(make_float2(b.x, b.y));
    r.h[3] = __float22bfloat162_rn(make_float2(b.z, b.w));
    return r.v;
}
#define MFMA16(a, b, c) __builtin_amdgcn_mfma_f32_16x16x32_bf16((a), (b), (c), 0, 0, 0)

// =========================================================================
// Kernel 1 (prep) — identical to R10 (known-good), sections by blockIdx:
//  [0,qb)        q = tanh(user @ Wq^T + bq) -> q_ws
//  qb            bkz = S*(bk + Wk@attr), bvz = S*bv
//  (qb, qb+8]    Wk,Wv -> bf16 XOR-swizzled frag chunks -> wf_ws
//  (qb+8, qb+48] zero out (atomic target)
//  rest          item/opin tables -> bf16 chunks (224 blocks)
// =========================================================================
__global__ void finerec_prep(
    const float* __restrict__ user_emb, const float* __restrict__ attr,
    const float* __restrict__ Wq, const float* __restrict__ bq,
    const float* __restrict__ Wk, const float* __restrict__ bk,
    const float* __restrict__ Wv, const float* __restrict__ bv,
    const float* __restrict__ item_table, const float* __restrict__ opin_table,
    float* __restrict__ q_ws, float* __restrict__ bkz_ws, float* __restrict__ bvz_ws,
    short* __restrict__ wf_ws, short* __restrict__ itb, short* __restrict__ opb,
    float* __restrict__ out, int U, int n_item, int n_opi, int qb)
{
    const int bx = blockIdx.x, tid = threadIdx.x;
    if (bx >= qb + 49) {                     // ---- table cast to bf16 chunks ----
        const int gid = (bx - qb - 49) * 256 + tid;
        const int stride = 224 * 256;
        const int tci = n_item * 16, tc = (n_item + n_opi) * 16;
        for (int c = gid; c < tc; c += stride) {
            if (c < tci) {
                const float* src = item_table + (size_t)c * 8;
                ((bf16x8*)itb)[c] = pack2(*(const float4*)src, *(const float4*)(src + 4));
            } else {
                const float* src = opin_table + (size_t)(c - tci) * 8;
                ((bf16x8*)opb)[c - tci] = pack2(*(const float4*)src, *(const float4*)(src + 4));
            }
        }
        return;
    }
    if (bx >= qb + 9) {                      // ---- zero the atomic output ----
        const int gid = (bx - qb - 9) * 256 + tid;
        float4 z = {0.0f, 0.0f, 0.0f, 0.0f};
        for (int i = gid; i < U * 32; i += 40 * 256) ((float4*)out)[i] = z;
        return;
    }
    if (bx >= qb + 1) {                      // ---- weight cast: 8 blocks ----
        const int bi = bx - qb - 1;
#pragma unroll
        for (int t = 0; t < 2; ++t) {
            const int g = bi * 512 + t * 256 + tid;           // 0..4095
            const int mat = g >> 11, gg = g & 2047, r = gg >> 4, c = gg & 15;
            const float* src = (mat ? Wv : Wk) + r * 128 + c * 8;
            ((bf16x8*)wf_ws)[(mat << 11) + (r << 4) + (c ^ (r & 15))] =
                pack2(*(const float4*)src, *(const float4*)(src + 4));
        }
        return;
    }
    if (bx == qb) {                          // ---- pre-scaled biases ----
        if (tid < 128) {
            const float* wr = Wk + tid * 128;
            float s = bk[tid];
            for (int k = 0; k < 128; k += 4) {
                float4 w4 = *(const float4*)(wr + k);
                float4 a4 = *(const float4*)(attr + k);
                s += w4.x * a4.x + w4.y * a4.y + w4.z * a4.z + w4.w * a4.w;
            }
            bkz_ws[tid] = s * S_2LOG2E;
        } else if (tid < 256) {
            bvz_ws[tid - 128] = bv[tid - 128] * S_2LOG2E;
        }
        return;
    }
    // ---- q: 64 users per block (16 per wave) ----
    const int wv = tid >> 6, lane = tid & 63;
    const int l15 = lane & 15, quad = lane >> 4;
    const int u0 = (bx * 4 + wv) * 16;
    int ur = u0 + l15; if (ur >= U) ur = U - 1;
    const float* up = user_emb + (size_t)ur * 128 + quad * 8;
    bf16x8 af[4];
#pragma unroll
    for (int ks = 0; ks < 4; ++ks)
        af[ks] = pack2(*(const float4*)(up + ks * 32), *(const float4*)(up + ks * 32 + 4));
#pragma unroll
    for (int nt = 0; nt < 8; ++nt) {
        const int n = nt * 16 + l15;
        const float* wp = Wq + n * 128 + quad * 8;
        f32x4 acc = {0, 0, 0, 0};
#pragma unroll
        for (int ks = 0; ks < 4; ++ks) {
            bf16x8 bf = pack2(*(const float4*)(wp + ks * 32), *(const float4*)(wp + ks * 32 + 4));
            acc = MFMA16(af[ks], bf, acc);
        }
        const float bqv = bq[n];
#pragma unroll
        for (int r = 0; r < 4; ++r) {
            int row = u0 + quad * 4 + r;
            if (row < U) q_ws[row * 128 + nt * 16 + l15] = tanh_fast(acc[r] + bqv);
        }
    }
}

// =========================================================================
// Kernel 2 (main): R10 structure + software pipelining:
//  - opin gather hoisted ABOVE the K pass (latency covered by K compute)
//  - next job's seq indices prefetched at body top (covered by whole job)
// Persistent 512x1024, launch_bounds(1024,4) -> 64-VGPR cap, 73 KB LDS ->
// 2 blocks/CU = 32 waves/CU. Quarter-user jobs, rolled nt, MFMA linearity
// in V pass, bf16 pre-cast tables, exp2-form tanh. atomicAdd into zeroed out.
// =========================================================================
__global__ __launch_bounds__(1024, 4) void finerec_main(
    const int* __restrict__ item_seqs, const int* __restrict__ opin_seqs,
    const float* __restrict__ q_ws, const float* __restrict__ bkz_ws,
    const float* __restrict__ bvz_ws, const short* __restrict__ wf_ws,
    const short* __restrict__ itb, const short* __restrict__ opb,
    float* __restrict__ out, int U, int L)
{
    __shared__ __align__(16) short wlds[32768];   // Wk + Wv frag chunks, XOR-swizzled
    __shared__ float q_lds[16 * 128];
    __shared__ float bkz_lds[128], bvz_lds[128];

    const int tid = threadIdx.x;
    const int wv = tid >> 6, lane = tid & 63, l15 = lane & 15, quad = lane >> 4;

    const bf16x8* wsrc = (const bf16x8*)wf_ws;
    bf16x8* wldsv = (bf16x8*)wlds;
#pragma unroll
    for (int i = 0; i < 4; ++i)
        wldsv[i * 1024 + tid] = wsrc[i * 1024 + tid];
    if (tid < 128)      bkz_lds[tid]       = bkz_ws[tid];
    else if (tid < 256) bvz_lds[tid - 128] = bvz_ws[tid - 128];
    __syncthreads();   // the ONLY block barrier

    const int nwaves = gridDim.x * 16;
    const int njobs  = 4 * U;
    const bool ldlane = (lane < 16);

    int job = blockIdx.x * 16 + wv;
    if (job >= njobs) return;   // wave-uniform, after the barrier

    // ---- prologue: load this job's indices ----
    int vi = 0, vo = 0;
    {
        const int u = job >> 2, rb = (job & 3) * 16;
        if (ldlane && rb + lane < L) {
            vi = item_seqs[u * L + rb + lane];
            vo = opin_seqs[u * L + rb + lane];
        }
    }

#pragma unroll 1
    while (job < njobs) {
        const int u = job >> 2;
        const int nx = job + nwaves;

        // ---- prefetch next job's indices (landing covered by this job) ----
        int vi_n = 0, vo_n = 0;
        if (nx < njobs) {
            const int un = nx >> 2, rbn = (nx & 3) * 16;
            if (ldlane && rbn + lane < L) {
                vi_n = item_seqs[un * L + rbn + lane];
                vo_n = opin_seqs[un * L + rbn + lane];
            }
        }

        const unsigned long long mb = __ballot(vi > 0);

        // ---- stage this job's q row (intra-wave RAW, lgkmcnt-ordered) ----
        q_lds[wv * 128 + lane]      = q_ws[u * 128 + lane];
        q_lds[wv * 128 + 64 + lane] = q_ws[u * 128 + 64 + lane];

        // ---- gather item AND opin rows up front (opin latency hidden by K) ----
        const int idx = __shfl(vi, l15);
        const int od  = __shfl(vo, l15);
        bf16x8 ai[4], ao[4];
        {
            const bf16x8* pi = (const bf16x8*)itb + (size_t)idx * 16 + quad;
            const bf16x8* po = (const bf16x8*)opb + (size_t)od * 16 + quad;
#pragma unroll
            for (int ks = 0; ks < 4; ++ks) { ai[ks] = pi[ks * 4]; ao[ks] = po[ks * 4]; }
        }

        // ---- K pass (attr folded into bkz); rolled nt ----
        float w[4] = {0, 0, 0, 0};
#pragma unroll 1
        for (int nt = 0; nt < 8; ++nt) {
            const int n = nt * 16 + l15;
            f32x4 c = {0, 0, 0, 0};
#pragma unroll
            for (int ks = 0; ks < 4; ++ks)
                c = MFMA16(ai[ks], wldsv[(n << 4) + ((ks * 4 + quad) ^ (n & 15))], c);
            const float qv  = q_lds[wv * 128 + n];
            const float bkz = bkz_lds[n];
#pragma unroll
            for (int r = 0; r < 4; ++r)
                w[r] = fmaf(qv, tanh_z(fmaf(c[r], S_2LOG2E, bkz)), w[r]);
        }
        // ---- w: reduce over 16 cols within quad + padding mask ----
#pragma unroll
        for (int r = 0; r < 4; ++r) {
            float t = w[r];
            t += __shfl_xor(t, 1); t += __shfl_xor(t, 2);
            t += __shfl_xor(t, 4); t += __shfl_xor(t, 8);
            w[r] = ((mb >> (quad * 4 + r)) & 1ull) ? t : 0.0f;
        }
        // ---- V pass: c = (item + opin) @ Wv via chained MFMAs (linearity) ----
        float s0 = 0.0f, s1 = 0.0f;
#pragma unroll 1
        for (int nt = 0; nt < 8; ++nt) {
            const int n = nt * 16 + l15;
            f32x4 c = {0, 0, 0, 0};
#pragma unroll
            for (int ks = 0; ks < 4; ++ks) {
                bf16x8 wf = wldsv[2048 + (n << 4) + ((ks * 4 + quad) ^ (n & 15))];
                c = MFMA16(ai[ks], wf, c);
                c = MFMA16(ao[ks], wf, c);
            }
            const float bvz = bvz_lds[n];
            float acc = 0.0f;
#pragma unroll
            for (int r = 0; r < 4; ++r)
                acc = fmaf(w[r], tanh_z(fmaf(c[r], S_2LOG2E, bvz)), acc);
            acc += __shfl_xor(acc, 16);
            acc += __shfl_xor(acc, 32);
            const bool mine = (quad == (nt >> 1));
            s0 += (mine && !(nt & 1)) ? acc : 0.0f;
            s1 += (mine &&  (nt & 1)) ? acc : 0.0f;
        }
        atomicAdd(out + u * 128 + quad * 32 + l15, s0);
        atomicAdd(out + u * 128 + quad * 32 + 16 + l15, s1);

        vi = vi_n; vo = vo_n; job = nx;
    }
}

extern "C" void kernel_launch(void* const* d_in, const int* in_sizes, int n_in,
                              void* d_out, int out_size, void* d_ws, size_t ws_size,
                              hipStream_t stream) {
    const float* item_table = (const float*)d_in[0];
    const float* opin_table = (const float*)d_in[1];
    const float* user_emb   = (const float*)d_in[2];
    const float* attr       = (const float*)d_in[3];
    const float* Wq = (const float*)d_in[4];
    const float* bq = (const float*)d_in[5];
    const float* Wk = (const float*)d_in[6];
    const float* bk = (const float*)d_in[7];
    const float* Wv = (const float*)d_in[8];
    const float* bv = (const float*)d_in[9];
    const int* item_seqs = (const int*)d_in[10];
    const int* opin_seqs = (const int*)d_in[11];
    float* out = (float*)d_out;

    const int U = in_sizes[2] / 128;        // 10000
    const int L = in_sizes[10] / U;         // 50
    const int n_item = in_sizes[0] / 128;   // 50000
    const int n_opi  = in_sizes[1] / 128;   // 5000

    // ---- ws layout ----
    char* w = (char*)d_ws;
    float* q_ws   = (float*)w;               w += (size_t)U * 128 * 4;
    float* bkz_ws = (float*)w;               w += 512;
    float* bvz_ws = (float*)w;               w += 512;
    short* wf_ws  = (short*)w;               w += 4096 * 16;
    short* itb    = (short*)w;               w += (size_t)n_item * 128 * 2;
    short* opb    = (short*)w;               w += (size_t)n_opi * 128 * 2;

    const int qb = (U + 63) / 64;
    finerec_prep<<<qb + 49 + 224, 256, 0, stream>>>(
        user_emb, attr, Wq, bq, Wk, bk, Wv, bv, item_table, opin_table,
        q_ws, bkz_ws, bvz_ws, wf_ws, itb, opb, out, U, n_item, n_opi, qb);

    finerec_main<<<512, 1024, 0, stream>>>(
        item_seqs, opin_seqs, q_ws, bkz_ws, bvz_ws, wf_ws, itb, opb, out, U, L);
}

// Round 12
// 188.410 us; speedup vs baseline: 1.0205x; 1.0205x over previous
//
#include <hip/hip_runtime.h>
#include <hip/hip_bf16.h>
#include <stdint.h>

typedef __attribute__((ext_vector_type(8))) short bf16x8;
typedef __attribute__((ext_vector_type(4))) float f32x4;

#define S_2LOG2E 2.8853900817779268f   // 2*log2(e): tanh(x)=1-2/(2^(x*S)+1)

#if __has_builtin(__builtin_amdgcn_exp2f)
#define EXP2F(x) __builtin_amdgcn_exp2f(x)
#else
#define EXP2F(x) __expf((x) * 0.6931471805599453f)
#endif
#if __has_builtin(__builtin_amdgcn_rcpf)
#define RCPF(x) __builtin_amdgcn_rcpf(x)
#else
#define RCPF(x) (1.0f / (x))
#endif

// tanh given pre-scaled argument z = S*(x) : returns tanh(x)
__device__ __forceinline__ float tanh_z(float z) {
    float e = EXP2F(z);
    float r = RCPF(e + 1.0f);
    return fmaf(-2.0f, r, 1.0f);
}
__device__ __forceinline__ float tanh_fast(float x) {   // prep only
    float e = __expf(2.0f * x);
    return 1.0f - 2.0f / (e + 1.0f);
}

// ---- bf16 pack via native v_cvt_pk_bf16_f32 (RNE) ----
__device__ __forceinline__ bf16x8 pack2(float4 a, float4 b) {
    union { bf16x8 v; __hip_bfloat162 h[4]; } r;
    r.h[0] = __float22bfloat162_rn(make_float2(a.x, a.y));
    r.h[1] = __float22bfloat162_rn(make_float2(a.z, a.w));
    r.h[2] = __float22bfloat162_rn(make_float2(b.x, b.y));
    r.h[3] = __float22bfloat162_rn(make_float2(b.z, b.w));
    return r.v;
}
#define MFMA16(a, b, c) __builtin_amdgcn_mfma_f32_16x16x32_bf16((a), (b), (c), 0, 0, 0)

// =========================================================================
// Kernel 1 (prep) — identical to R10 (known-good), sections by blockIdx:
//  [0,qb)        q = tanh(user @ Wq^T + bq) -> q_ws
//  qb            bkz = S*(bk + Wk@attr), bvz = S*bv
//  (qb, qb+8]    Wk,Wv -> bf16 XOR-swizzled frag chunks -> wf_ws
//  (qb+8, qb+48] zero out (atomic target)
//  rest          item/opin tables -> bf16 chunks (224 blocks)
// =========================================================================
__global__ void finerec_prep(
    const float* __restrict__ user_emb, const float* __restrict__ attr,
    const float* __restrict__ Wq, const float* __restrict__ bq,
    const float* __restrict__ Wk, const float* __restrict__ bk,
    const float* __restrict__ Wv, const float* __restrict__ bv,
    const float* __restrict__ item_table, const float* __restrict__ opin_table,
    float* __restrict__ q_ws, float* __restrict__ bkz_ws, float* __restrict__ bvz_ws,
    short* __restrict__ wf_ws, short* __restrict__ itb, short* __restrict__ opb,
    float* __restrict__ out, int U, int n_item, int n_opi, int qb)
{
    const int bx = blockIdx.x, tid = threadIdx.x;
    if (bx >= qb + 49) {                     // ---- table cast to bf16 chunks ----
        const int gid = (bx - qb - 49) * 256 + tid;
        const int stride = 224 * 256;
        const int tci = n_item * 16, tc = (n_item + n_opi) * 16;
        for (int c = gid; c < tc; c += stride) {
            if (c < tci) {
                const float* src = item_table + (size_t)c * 8;
                ((bf16x8*)itb)[c] = pack2(*(const float4*)src, *(const float4*)(src + 4));
            } else {
                const float* src = opin_table + (size_t)(c - tci) * 8;
                ((bf16x8*)opb)[c - tci] = pack2(*(const float4*)src, *(const float4*)(src + 4));
            }
        }
        return;
    }
    if (bx >= qb + 9) {                      // ---- zero the atomic output ----
        const int gid = (bx - qb - 9) * 256 + tid;
        float4 z = {0.0f, 0.0f, 0.0f, 0.0f};
        for (int i = gid; i < U * 32; i += 40 * 256) ((float4*)out)[i] = z;
        return;
    }
    if (bx >= qb + 1) {                      // ---- weight cast: 8 blocks ----
        const int bi = bx - qb - 1;
#pragma unroll
        for (int t = 0; t < 2; ++t) {
            const int g = bi * 512 + t * 256 + tid;           // 0..4095
            const int mat = g >> 11, gg = g & 2047, r = gg >> 4, c = gg & 15;
            const float* src = (mat ? Wv : Wk) + r * 128 + c * 8;
            ((bf16x8*)wf_ws)[(mat << 11) + (r << 4) + (c ^ (r & 15))] =
                pack2(*(const float4*)src, *(const float4*)(src + 4));
        }
        return;
    }
    if (bx == qb) {                          // ---- pre-scaled biases ----
        if (tid < 128) {
            const float* wr = Wk + tid * 128;
            float s = bk[tid];
            for (int k = 0; k < 128; k += 4) {
                float4 w4 = *(const float4*)(wr + k);
                float4 a4 = *(const float4*)(attr + k);
                s += w4.x * a4.x + w4.y * a4.y + w4.z * a4.z + w4.w * a4.w;
            }
            bkz_ws[tid] = s * S_2LOG2E;
        } else if (tid < 256) {
            bvz_ws[tid - 128] = bv[tid - 128] * S_2LOG2E;
        }
        return;
    }
    // ---- q: 64 users per block (16 per wave) ----
    const int wv = tid >> 6, lane = tid & 63;
    const int l15 = lane & 15, quad = lane >> 4;
    const int u0 = (bx * 4 + wv) * 16;
    int ur = u0 + l15; if (ur >= U) ur = U - 1;
    const float* up = user_emb + (size_t)ur * 128 + quad * 8;
    bf16x8 af[4];
#pragma unroll
    for (int ks = 0; ks < 4; ++ks)
        af[ks] = pack2(*(const float4*)(up + ks * 32), *(const float4*)(up + ks * 32 + 4));
#pragma unroll
    for (int nt = 0; nt < 8; ++nt) {
        const int n = nt * 16 + l15;
        const float* wp = Wq + n * 128 + quad * 8;
        f32x4 acc = {0, 0, 0, 0};
#pragma unroll
        for (int ks = 0; ks < 4; ++ks) {
            bf16x8 bf = pack2(*(const float4*)(wp + ks * 32), *(const float4*)(wp + ks * 32 + 4));
            acc = MFMA16(af[ks], bf, acc);
        }
        const float bqv = bq[n];
#pragma unroll
        for (int r = 0; r < 4; ++r) {
            int row = u0 + quad * 4 + r;
            if (row < U) q_ws[row * 128 + nt * 16 + l15] = tanh_fast(acc[r] + bqv);
        }
    }
}

// =========================================================================
// Kernel 2 (main): EXACT R10 structure (the verified 94 µs body — for-loop
// job stride, opin gathered after K pass, no manual prefetch) with ONE
// change: nt loops at unroll 2 -> two independent ds_read/MFMA/tanh strings
// in flight per wave (ILP). Persistent 512x1024, launch_bounds(1024,4) ->
// 64-VGPR cap, 73 KB LDS -> 2 blocks/CU = 32 waves/CU. Quarter-user jobs,
// MFMA linearity in V, bf16 tables, exp2 tanh, atomicAdd into zeroed out.
// =========================================================================
__global__ __launch_bounds__(1024, 4) void finerec_main(
    const int* __restrict__ item_seqs, const int* __restrict__ opin_seqs,
    const float* __restrict__ q_ws, const float* __restrict__ bkz_ws,
    const float* __restrict__ bvz_ws, const short* __restrict__ wf_ws,
    const short* __restrict__ itb, const short* __restrict__ opb,
    float* __restrict__ out, int U, int L)
{
    __shared__ __align__(16) short wlds[32768];   // Wk + Wv frag chunks, XOR-swizzled
    __shared__ float q_lds[16 * 128];
    __shared__ float bkz_lds[128], bvz_lds[128];

    const int tid = threadIdx.x;
    const int wv = tid >> 6, lane = tid & 63, l15 = lane & 15, quad = lane >> 4;

    const bf16x8* wsrc = (const bf16x8*)wf_ws;
    bf16x8* wldsv = (bf16x8*)wlds;
#pragma unroll
    for (int i = 0; i < 4; ++i)
        wldsv[i * 1024 + tid] = wsrc[i * 1024 + tid];
    if (tid < 128)      bkz_lds[tid]       = bkz_ws[tid];
    else if (tid < 256) bvz_lds[tid - 128] = bvz_ws[tid - 128];
    __syncthreads();   // the ONLY block barrier

    const int nwaves = gridDim.x * 16;
    const int njobs  = 4 * U;

#pragma unroll 1
    for (int job = blockIdx.x * 16 + wv; job < njobs; job += nwaves) {
        const int u  = job >> 2;
        const int rb = (job & 3) * 16;   // rows rb..rb+15 of user u

        int vi = 0, vo = 0;
        if (lane < 16 && rb + lane < L) {
            vi = item_seqs[u * L + rb + lane];
            vo = opin_seqs[u * L + rb + lane];
        }
        const unsigned long long mb = __ballot(vi > 0);

        q_lds[wv * 128 + lane]      = q_ws[u * 128 + lane];
        q_lds[wv * 128 + 64 + lane] = q_ws[u * 128 + 64 + lane];

        // ---- gather item rows -> A-frags ----
        const int idx = __shfl(vi, l15);
        bf16x8 ai[4];
        {
            const bf16x8* pb = (const bf16x8*)itb + (size_t)idx * 16 + quad;
#pragma unroll
            for (int ks = 0; ks < 4; ++ks) ai[ks] = pb[ks * 4];
        }

        // ---- K pass (attr folded into bkz); nt at unroll 2 (ILP) ----
        float w[4] = {0, 0, 0, 0};
#pragma unroll 2
        for (int nt = 0; nt < 8; ++nt) {
            const int n = nt * 16 + l15;
            f32x4 c = {0, 0, 0, 0};
#pragma unroll
            for (int ks = 0; ks < 4; ++ks)
                c = MFMA16(ai[ks], wldsv[(n << 4) + ((ks * 4 + quad) ^ (n & 15))], c);
            const float qv  = q_lds[wv * 128 + n];
            const float bkz = bkz_lds[n];
#pragma unroll
            for (int r = 0; r < 4; ++r)
                w[r] = fmaf(qv, tanh_z(fmaf(c[r], S_2LOG2E, bkz)), w[r]);
        }
        // ---- w: reduce over 16 cols within quad + padding mask ----
#pragma unroll
        for (int r = 0; r < 4; ++r) {
            float t = w[r];
            t += __shfl_xor(t, 1); t += __shfl_xor(t, 2);
            t += __shfl_xor(t, 4); t += __shfl_xor(t, 8);
            w[r] = ((mb >> (quad * 4 + r)) & 1ull) ? t : 0.0f;
        }
        // ---- gather opin rows -> second A-frags (linearity: no add/repack) ----
        const int od = __shfl(vo, l15);
        bf16x8 ao[4];
        {
            const bf16x8* pb = (const bf16x8*)opb + (size_t)od * 16 + quad;
#pragma unroll
            for (int ks = 0; ks < 4; ++ks) ao[ks] = pb[ks * 4];
        }
        // ---- V pass: c = (item + opin) @ Wv via chained MFMAs; unroll 2 ----
        float s0 = 0.0f, s1 = 0.0f;
#pragma unroll 2
        for (int nt = 0; nt < 8; ++nt) {
            const int n = nt * 16 + l15;
            f32x4 c = {0, 0, 0, 0};
#pragma unroll
            for (int ks = 0; ks < 4; ++ks) {
                bf16x8 wf = wldsv[2048 + (n << 4) + ((ks * 4 + quad) ^ (n & 15))];
                c = MFMA16(ai[ks], wf, c);
                c = MFMA16(ao[ks], wf, c);
            }
            const float bvz = bvz_lds[n];
            float acc = 0.0f;
#pragma unroll
            for (int r = 0; r < 4; ++r)
                acc = fmaf(w[r], tanh_z(fmaf(c[r], S_2LOG2E, bvz)), acc);
            acc += __shfl_xor(acc, 16);
            acc += __shfl_xor(acc, 32);
            const bool mine = (quad == (nt >> 1));
            s0 += (mine && !(nt & 1)) ? acc : 0.0f;
            s1 += (mine &&  (nt & 1)) ? acc : 0.0f;
        }
        atomicAdd(out + u * 128 + quad * 32 + l15, s0);
        atomicAdd(out + u * 128 + quad * 32 + 16 + l15, s1);
    }
}

extern "C" void kernel_launch(void* const* d_in, const int* in_sizes, int n_in,
                              void* d_out, int out_size, void* d_ws, size_t ws_size,
                              hipStream_t stream) {
    const float* item_table = (const float*)d_in[0];
    const float* opin_table = (const float*)d_in[1];
    const float* user_emb   = (const float*)d_in[2];
    const float* attr       = (const float*)d_in[3];
    const float* Wq = (const float*)d_in[4];
    const float* bq = (const float*)d_in[5];
    const float* Wk = (const float*)d_in[6];
    const float* bk = (const float*)d_in[7];
    const float* Wv = (const float*)d_in[8];
    const float* bv = (const float*)d_in[9];
    const int* item_seqs = (const int*)d_in[10];
    const int* opin_seqs = (const int*)d_in[11];
    float* out = (float*)d_out;

    const int U = in_sizes[2] / 128;        // 10000
    const int L = in_sizes[10] / U;         // 50
    const int n_item = in_sizes[0] / 128;   // 50000
    const int n_opi  = in_sizes[1] / 128;   // 5000

    // ---- ws layout ----
    char* w = (char*)d_ws;
    float* q_ws   = (float*)w;               w += (size_t)U * 128 * 4;
    float* bkz_ws = (float*)w;               w += 512;
    float* bvz_ws = (float*)w;               w += 512;
    short* wf_ws  = (short*)w;               w += 4096 * 16;
    short* itb    = (short*)w;               w += (size_t)n_item * 128 * 2;
    short* opb    = (short*)w;               w += (size_t)n_opi * 128 * 2;

    const int qb = (U + 63) / 64;
    finerec_prep<<<qb + 49 + 224, 256, 0, stream>>>(
        user_emb, attr, Wq, bq, Wk, bk, Wv, bv, item_table, opin_table,
        q_ws, bkz_ws, bvz_ws, wf_ws, itb, opb, out, U, n_item, n_opi, qb);

    finerec_main<<<512, 1024, 0, stream>>>(
        item_seqs, opin_seqs, q_ws, bkz_ws, bvz_ws, wf_ws, itb, opb, out, U, L);
}